// Round 1
// baseline (111.140 us; speedup 1.0000x reference)
//
#include <hip/hip_runtime.h>
#include <hip/hip_bf16.h>
#include <math.h>

// OHEM BCE-with-logits, shape (4,1,192,192,192) f32, scalar f32 output.
// Strategy: one streaming pass builds a 4096-bin value histogram
// (count + sum) of negative losses + pos count/sum; a 1-block finalize
// kernel suffix-scans the histogram to get the top-k negative sum.

#define NBINS 4096
#define BIN_SCALE 256.0f        // bin = loss * 256 -> covers [0, 16)
#define FIXED_SCALE 1048576.0f  // 2^20 fixed point for LDS-packed sums
#define CNT_SHIFT 40

__device__ __forceinline__ float bce_loss(float x, float t) {
    // max(x,0) - x*t + log1p(exp(-|x|)), numerically stable
    return fmaxf(x, 0.0f) - x * t + log1pf(expf(-fabsf(x)));
}

extern "C" __global__ __launch_bounds__(256) void ohem_pass1(
    const float* __restrict__ logits, const float* __restrict__ targets,
    unsigned int* __restrict__ g_cnt, float* __restrict__ g_sum,
    unsigned int* __restrict__ g_npos, float* __restrict__ g_psum,
    int n4, int n_total)
{
    __shared__ unsigned long long h[NBINS];   // 32 KiB
    __shared__ unsigned int s_pcnt[4];
    __shared__ float s_psum[4];

    for (int i = threadIdx.x; i < NBINS; i += 256) h[i] = 0ULL;
    __syncthreads();

    const float4* L4 = (const float4*)logits;
    const float4* T4 = (const float4*)targets;
    unsigned int pcnt = 0;
    float psum = 0.0f;
    const int stride = gridDim.x * blockDim.x;

    for (int i = blockIdx.x * blockDim.x + threadIdx.x; i < n4; i += stride) {
        float4 x4 = L4[i];
        float4 t4 = T4[i];
        float xs[4] = {x4.x, x4.y, x4.z, x4.w};
        float ts[4] = {t4.x, t4.y, t4.z, t4.w};
        #pragma unroll
        for (int j = 0; j < 4; ++j) {
            float loss = bce_loss(xs[j], ts[j]);
            if (ts[j] > 0.5f) {
                pcnt++;
                psum += loss;
            } else {
                int bin = (int)(loss * BIN_SCALE);
                bin = bin < 0 ? 0 : (bin > NBINS - 1 ? NBINS - 1 : bin);
                unsigned long long pack = (1ULL << CNT_SHIFT) +
                    (unsigned long long)(loss * FIXED_SCALE);
                atomicAdd(&h[bin], pack);
            }
        }
    }
    // tail (n_total not divisible by 4) -- not hit for this shape, kept for safety
    if (blockIdx.x == 0) {
        int rem_start = n4 * 4;
        for (int i = rem_start + threadIdx.x; i < n_total; i += 256) {
            float x = logits[i], t = targets[i];
            float loss = bce_loss(x, t);
            if (t > 0.5f) { pcnt++; psum += loss; }
            else {
                int bin = (int)(loss * BIN_SCALE);
                bin = bin < 0 ? 0 : (bin > NBINS - 1 ? NBINS - 1 : bin);
                unsigned long long pack = (1ULL << CNT_SHIFT) +
                    (unsigned long long)(loss * FIXED_SCALE);
                atomicAdd(&h[bin], pack);
            }
        }
    }
    __syncthreads();

    // flush LDS histogram to global
    for (int i = threadIdx.x; i < NBINS; i += 256) {
        unsigned long long p = h[i];
        if (p) {
            unsigned int c = (unsigned int)(p >> CNT_SHIFT);
            float s = (float)(p & ((1ULL << CNT_SHIFT) - 1)) * (1.0f / FIXED_SCALE);
            atomicAdd(&g_cnt[i], c);
            atomicAdd(&g_sum[i], s);
        }
    }

    // reduce positive count/sum: wave64 shuffle, then cross-wave via LDS
    #pragma unroll
    for (int off = 32; off > 0; off >>= 1) {
        pcnt += __shfl_down(pcnt, off);
        psum += __shfl_down(psum, off);
    }
    int wave = threadIdx.x >> 6;
    if ((threadIdx.x & 63) == 0) { s_pcnt[wave] = pcnt; s_psum[wave] = psum; }
    __syncthreads();
    if (threadIdx.x == 0) {
        unsigned int c = 0; float s = 0.0f;
        #pragma unroll
        for (int w = 0; w < 4; ++w) { c += s_pcnt[w]; s += s_psum[w]; }
        if (c) atomicAdd(g_npos, c);
        atomicAdd(g_psum, s);
    }
}

extern "C" __global__ __launch_bounds__(256) void ohem_finalize(
    const unsigned int* __restrict__ g_cnt, const float* __restrict__ g_sum,
    const unsigned int* __restrict__ g_npos, const float* __restrict__ g_psum,
    float* __restrict__ out, int n_total)
{
    const int BPT = NBINS / 256; // 16 bins per thread
    __shared__ unsigned int sh_c[256];
    __shared__ float sh_s[256];
    __shared__ unsigned int suf_c[256];
    __shared__ float suf_s[256];

    int tid = threadIdx.x;
    unsigned int lc[BPT];
    float ls[BPT];
    unsigned int tc = 0;
    float tsum = 0.0f;
    #pragma unroll
    for (int j = 0; j < BPT; ++j) {
        lc[j] = g_cnt[tid * BPT + j];
        ls[j] = g_sum[tid * BPT + j];
        tc += lc[j];
        tsum += ls[j];
    }
    sh_c[tid] = tc;
    sh_s[tid] = tsum;
    __syncthreads();

    if (tid == 0) {
        // exclusive suffix totals over 256 thread-chunks (serial: trivial)
        unsigned int rc = 0; float rs = 0.0f;
        for (int i = 255; i >= 0; --i) {
            suf_c[i] = rc; suf_s[i] = rs;
            rc += sh_c[i]; rs += sh_s[i];
        }
    }
    __syncthreads();

    unsigned int n_pos = *g_npos;
    unsigned int n_neg = (unsigned int)n_total - n_pos;
    float pos_mean = (n_pos > 0) ? (*g_psum / (float)n_pos) : 0.0f;

    if (n_neg == 0) {
        if (tid == 0) out[0] = pos_mean;  // neg_mean = 0
        return;
    }

    // k = max(MIN_NEG, rint(0.1 * n_neg)); k = min(k, n_neg)
    float nf = (float)n_neg;             // RNE conversion, matches .astype(f32)
    int k = (int)rintf(nf * 0.1f);       // RNE, matches jnp.round
    if (k < 1024) k = 1024;
    if ((unsigned int)k > n_neg) k = (int)n_neg;

    // walk own chunk from the top bin down; exactly one (tid, j) crosses k
    unsigned int run_c = suf_c[tid];
    float run_s = suf_s[tid];
    #pragma unroll
    for (int j = BPT - 1; j >= 0; --j) {
        unsigned int c = lc[j];
        float s = ls[j];
        if (c > 0 && run_c < (unsigned int)k && run_c + c >= (unsigned int)k) {
            unsigned int m = (unsigned int)k - run_c;
            float meanb = s / (float)c;
            float neg_sum = run_s + (float)m * meanb;
            float neg_mean = neg_sum / (float)k;
            out[0] = pos_mean + neg_mean;
        }
        run_c += c;
        run_s += s;
    }
}

extern "C" void kernel_launch(void* const* d_in, const int* in_sizes, int n_in,
                              void* d_out, int out_size, void* d_ws, size_t ws_size,
                              hipStream_t stream) {
    const float* logits  = (const float*)d_in[0];
    const float* targets = (const float*)d_in[1];
    float* out = (float*)d_out;
    int n_total = in_sizes[0];
    int n4 = n_total / 4;

    unsigned int* g_cnt  = (unsigned int*)d_ws;
    float*        g_sum  = (float*)((char*)d_ws + NBINS * 4);
    unsigned int* g_npos = (unsigned int*)((char*)d_ws + NBINS * 8);
    float*        g_psum = (float*)((char*)d_ws + NBINS * 8 + 4);

    hipMemsetAsync(d_ws, 0, NBINS * 8 + 8, stream);

    // 32 KiB LDS/block -> 5 blocks/CU by LDS; 1280 = 5 * 256 CUs, all resident
    ohem_pass1<<<1280, 256, 0, stream>>>(logits, targets, g_cnt, g_sum,
                                         g_npos, g_psum, n4, n_total);
    ohem_finalize<<<1, 256, 0, stream>>>(g_cnt, g_sum, g_npos, g_psum,
                                         out, n_total);
}

// Round 2
// 101.987 us; speedup vs baseline: 1.0897x; 1.0897x over previous
//
#include <hip/hip_runtime.h>
#include <hip/hip_bf16.h>
#include <math.h>

// OHEM BCE-with-logits, shape (4,1,192,192,192) f32, scalar f32 output.
//
// Key insight: negative loss = softplus(x) is MONOTONE in the logit x, so
// top-k selection can be done on a histogram of x directly -- no exp/log in
// the hot loop. Per-bin we store (count, sum of (x+8)) packed in one u64 LDS
// atomic. The finalize kernel evaluates softplus once per BIN (2048 evals)
// on the bin mean; within-bin error is O(softplus'' * binwidth^2) ~ 5e-7.
// Positives (2% of voxels) get an exact fast-intrinsic softplus(-x) path.

#define NBINS 2048
#define XOFF 8.0f               // bin range x in [-8, 8]
#define BIN_SCALE 128.0f        // (x+8)*128 -> [0, 2048)
#define FIX_SCALE 262144.0f     // 2^18 fixed point: (x+8)*2^18 <= 2^22
#define CNT_SHIFT 40

extern "C" __global__ __launch_bounds__(256) void ohem_pass1(
    const float* __restrict__ logits, const float* __restrict__ targets,
    unsigned int* __restrict__ g_cnt, float* __restrict__ g_sum,
    unsigned int* __restrict__ g_npos, float* __restrict__ g_psum,
    int n4, int n_total)
{
    __shared__ unsigned long long h[NBINS];   // 16 KiB
    __shared__ unsigned int s_pcnt[4];
    __shared__ float s_psum[4];

    for (int i = threadIdx.x; i < NBINS; i += 256) h[i] = 0ULL;
    __syncthreads();

    const float4* L4 = (const float4*)logits;
    const float4* T4 = (const float4*)targets;
    unsigned int pcnt = 0;
    float psum = 0.0f;
    const int stride = gridDim.x * blockDim.x;

    for (int i = blockIdx.x * blockDim.x + threadIdx.x; i < n4; i += stride) {
        float4 x4 = L4[i];
        float4 t4 = T4[i];
        float xs[4] = {x4.x, x4.y, x4.z, x4.w};
        float ts[4] = {t4.x, t4.y, t4.z, t4.w};
        #pragma unroll
        for (int j = 0; j < 4; ++j) {
            float x = xs[j];
            if (ts[j] > 0.5f) {
                // exact positive loss: softplus(-x), fast HW transcendentals
                pcnt++;
                psum += fmaxf(-x, 0.0f) + __logf(1.0f + __expf(-fabsf(x)));
            } else {
                float f = fmaxf(fmaf(x, BIN_SCALE, XOFF * BIN_SCALE), 0.0f);
                unsigned int bin = (unsigned int)f;
                bin = bin > NBINS - 1 ? NBINS - 1 : bin;
                unsigned int fix = (unsigned int)(f * (FIX_SCALE / BIN_SCALE));
                atomicAdd(&h[bin], (1ULL << CNT_SHIFT) + (unsigned long long)fix);
            }
        }
    }
    // tail (n_total % 4) -- not hit for this shape, kept for safety
    if (blockIdx.x == 0) {
        for (int i = n4 * 4 + threadIdx.x; i < n_total; i += 256) {
            float x = logits[i], t = targets[i];
            if (t > 0.5f) {
                pcnt++;
                psum += fmaxf(-x, 0.0f) + __logf(1.0f + __expf(-fabsf(x)));
            } else {
                float f = fmaxf(fmaf(x, BIN_SCALE, XOFF * BIN_SCALE), 0.0f);
                unsigned int bin = (unsigned int)f;
                bin = bin > NBINS - 1 ? NBINS - 1 : bin;
                unsigned int fix = (unsigned int)(f * (FIX_SCALE / BIN_SCALE));
                atomicAdd(&h[bin], (1ULL << CNT_SHIFT) + (unsigned long long)fix);
            }
        }
    }
    __syncthreads();

    // flush LDS histogram to global (count u32, x-sum as float)
    for (int i = threadIdx.x; i < NBINS; i += 256) {
        unsigned long long p = h[i];
        if (p) {
            unsigned int c = (unsigned int)(p >> CNT_SHIFT);
            float s = (float)(p & ((1ULL << CNT_SHIFT) - 1)) * (1.0f / FIX_SCALE);
            atomicAdd(&g_cnt[i], c);
            atomicAdd(&g_sum[i], s);   // sum of (x+8) for this bin
        }
    }

    // reduce positive count/sum: wave64 shuffle, then cross-wave via LDS
    #pragma unroll
    for (int off = 32; off > 0; off >>= 1) {
        pcnt += __shfl_down(pcnt, off);
        psum += __shfl_down(psum, off);
    }
    int wave = threadIdx.x >> 6;
    if ((threadIdx.x & 63) == 0) { s_pcnt[wave] = pcnt; s_psum[wave] = psum; }
    __syncthreads();
    if (threadIdx.x == 0) {
        unsigned int c = 0; float s = 0.0f;
        #pragma unroll
        for (int w = 0; w < 4; ++w) { c += s_pcnt[w]; s += s_psum[w]; }
        if (c) atomicAdd(g_npos, c);
        atomicAdd(g_psum, s);
    }
}

__device__ __forceinline__ float softplus_acc(float v) {
    return fmaxf(v, 0.0f) + log1pf(expf(-fabsf(v)));
}

extern "C" __global__ __launch_bounds__(256) void ohem_finalize(
    const unsigned int* __restrict__ g_cnt, const float* __restrict__ g_sum,
    const unsigned int* __restrict__ g_npos, const float* __restrict__ g_psum,
    float* __restrict__ out, int n_total)
{
    const int BPT = NBINS / 256; // 8 bins per thread
    __shared__ unsigned int sh_c[256];
    __shared__ float sh_s[256];
    __shared__ unsigned int suf_c[256];
    __shared__ float suf_s[256];

    int tid = threadIdx.x;
    unsigned int lc[BPT];
    float lloss[BPT];            // per-bin total loss: c * softplus(mean x)
    unsigned int tc = 0;
    float tsum = 0.0f;
    #pragma unroll
    for (int j = 0; j < BPT; ++j) {
        unsigned int c = g_cnt[tid * BPT + j];
        float s = g_sum[tid * BPT + j];
        lc[j] = c;
        float lb = 0.0f;
        if (c > 0) {
            float xbar = s / (float)c - XOFF;
            lb = (float)c * softplus_acc(xbar);
        }
        lloss[j] = lb;
        tc += c;
        tsum += lb;
    }
    sh_c[tid] = tc;
    sh_s[tid] = tsum;
    __syncthreads();

    if (tid == 0) {
        // exclusive suffix totals over the 256 thread-chunks
        unsigned int rc = 0; float rs = 0.0f;
        for (int i = 255; i >= 0; --i) {
            suf_c[i] = rc; suf_s[i] = rs;
            rc += sh_c[i]; rs += sh_s[i];
        }
    }
    __syncthreads();

    unsigned int n_pos = *g_npos;
    unsigned int n_neg = (unsigned int)n_total - n_pos;
    float pos_mean = (n_pos > 0) ? (*g_psum / (float)n_pos) : 0.0f;

    if (n_neg == 0) {
        if (tid == 0) out[0] = pos_mean;
        return;
    }

    // k = max(1024, rint(0.1 * n_neg)), clamped to n_neg (RNE matches jnp.round)
    float nf = (float)n_neg;
    int k = (int)rintf(nf * 0.1f);
    if (k < 1024) k = 1024;
    if ((unsigned int)k > n_neg) k = (int)n_neg;

    // walk own chunk from the top bin down; exactly one (tid, j) crosses k
    unsigned int run_c = suf_c[tid];
    float run_s = suf_s[tid];
    #pragma unroll
    for (int j = BPT - 1; j >= 0; --j) {
        unsigned int c = lc[j];
        float lb = lloss[j];
        if (c > 0 && run_c < (unsigned int)k && run_c + c >= (unsigned int)k) {
            unsigned int m = (unsigned int)k - run_c;
            float neg_sum = run_s + (float)m * (lb / (float)c);  // m * mean bin loss
            float neg_mean = neg_sum / (float)k;
            out[0] = pos_mean + neg_mean;
        }
        run_c += c;
        run_s += lb;
    }
}

extern "C" void kernel_launch(void* const* d_in, const int* in_sizes, int n_in,
                              void* d_out, int out_size, void* d_ws, size_t ws_size,
                              hipStream_t stream) {
    const float* logits  = (const float*)d_in[0];
    const float* targets = (const float*)d_in[1];
    float* out = (float*)d_out;
    int n_total = in_sizes[0];
    int n4 = n_total / 4;

    unsigned int* g_cnt  = (unsigned int*)d_ws;
    float*        g_sum  = (float*)((char*)d_ws + NBINS * 4);
    unsigned int* g_npos = (unsigned int*)((char*)d_ws + NBINS * 8);
    float*        g_psum = (float*)((char*)d_ws + NBINS * 8 + 4);

    hipMemsetAsync(d_ws, 0, NBINS * 8 + 8, stream);

    // 16 KiB LDS/block -> occupancy capped by waves: 8 blocks/CU.
    // 2048 = 8 * 256 CUs: whole grid resident, no tail.
    ohem_pass1<<<2048, 256, 0, stream>>>(logits, targets, g_cnt, g_sum,
                                         g_npos, g_psum, n4, n_total);
    ohem_finalize<<<1, 256, 0, stream>>>(g_cnt, g_sum, g_npos, g_psum,
                                         out, n_total);
}

// Round 3
// 62.689 us; speedup vs baseline: 1.7729x; 1.6269x over previous
//
#include <hip/hip_runtime.h>
#include <hip/hip_bf16.h>
#include <math.h>

// OHEM BCE-with-logits, shape (4,1,192,192,192) f32, scalar f32 output.
//
// R3: counts-ONLY histogram of the negative logits (softplus is monotone, so
// top-k selection works on x directly). 4096 bins over [-8,8) -> bin width
// 1/256. neg_sum is reconstructed as sum_b count_b * softplus(bin_center_b);
// within-bin error <= half-width (2e-3) << 5.5e-2 tolerance.
// This makes the hot-loop LDS op a non-returning ds_add_u32 (1 bank, ~2-way
// conflict = free) instead of a u64 2-bank RMW with ~4-way conflicts.

#define NBINS 4096
#define XOFF 8.0f
#define BIN_SCALE 256.0f        // (x+8)*256 -> [0, 4096)
#define INV_BIN 0.00390625f     // 1/256

extern "C" __global__ __launch_bounds__(1024) void ohem_pass1(
    const float* __restrict__ logits, const float* __restrict__ targets,
    unsigned int* __restrict__ g_cnt,
    unsigned int* __restrict__ g_npos, float* __restrict__ g_psum,
    int n8, int n_total)
{
    __shared__ unsigned int h[NBINS];   // 16 KiB
    __shared__ unsigned int s_pcnt[16];
    __shared__ float s_psum[16];

    for (int i = threadIdx.x; i < NBINS; i += 1024) h[i] = 0u;
    __syncthreads();

    const float4* L4 = (const float4*)logits;
    const float4* T4 = (const float4*)targets;
    unsigned int pcnt = 0;
    float psum = 0.0f;
    const int stride = gridDim.x * blockDim.x;

    for (int i = blockIdx.x * blockDim.x + threadIdx.x; i < n8; i += stride) {
        float4 xa = L4[2 * i];
        float4 xb = L4[2 * i + 1];
        float4 ta = T4[2 * i];
        float4 tb = T4[2 * i + 1];
        float xs[8] = {xa.x, xa.y, xa.z, xa.w, xb.x, xb.y, xb.z, xb.w};
        float ts[8] = {ta.x, ta.y, ta.z, ta.w, tb.x, tb.y, tb.z, tb.w};
        #pragma unroll
        for (int j = 0; j < 8; ++j) {
            float x = xs[j];
            if (ts[j] > 0.5f) {
                // exact positive loss: softplus(-x), fast HW transcendentals
                pcnt++;
                psum += fmaxf(-x, 0.0f) + __logf(1.0f + __expf(-fabsf(x)));
            } else {
                float f = fmaxf(fmaf(x, BIN_SCALE, XOFF * BIN_SCALE), 0.0f);
                unsigned int bin = (unsigned int)f;
                bin = bin > NBINS - 1 ? NBINS - 1 : bin;
                atomicAdd(&h[bin], 1u);   // non-returning ds_add_u32
            }
        }
    }
    // tail (n_total % 8) -- not hit for this shape, kept for safety
    if (blockIdx.x == 0) {
        for (int i = n8 * 8 + threadIdx.x; i < n_total; i += 1024) {
            float x = logits[i], t = targets[i];
            if (t > 0.5f) {
                pcnt++;
                psum += fmaxf(-x, 0.0f) + __logf(1.0f + __expf(-fabsf(x)));
            } else {
                float f = fmaxf(fmaf(x, BIN_SCALE, XOFF * BIN_SCALE), 0.0f);
                unsigned int bin = (unsigned int)f;
                bin = bin > NBINS - 1 ? NBINS - 1 : bin;
                atomicAdd(&h[bin], 1u);
            }
        }
    }
    __syncthreads();

    // flush LDS histogram to global
    for (int i = threadIdx.x; i < NBINS; i += 1024) {
        unsigned int c = h[i];
        if (c) atomicAdd(&g_cnt[i], c);
    }

    // reduce positive count/sum: wave64 shuffle, then cross-wave via LDS
    #pragma unroll
    for (int off = 32; off > 0; off >>= 1) {
        pcnt += __shfl_down(pcnt, off);
        psum += __shfl_down(psum, off);
    }
    int wave = threadIdx.x >> 6;
    if ((threadIdx.x & 63) == 0) { s_pcnt[wave] = pcnt; s_psum[wave] = psum; }
    __syncthreads();
    if (threadIdx.x == 0) {
        unsigned int c = 0; float s = 0.0f;
        #pragma unroll
        for (int w = 0; w < 16; ++w) { c += s_pcnt[w]; s += s_psum[w]; }
        if (c) atomicAdd(g_npos, c);
        atomicAdd(g_psum, s);
    }
}

__device__ __forceinline__ float softplus_acc(float v) {
    return fmaxf(v, 0.0f) + log1pf(expf(-fabsf(v)));
}

extern "C" __global__ __launch_bounds__(256) void ohem_finalize(
    const unsigned int* __restrict__ g_cnt,
    const unsigned int* __restrict__ g_npos, const float* __restrict__ g_psum,
    float* __restrict__ out, int n_total)
{
    const int BPT = NBINS / 256; // 16 bins per thread
    __shared__ unsigned int sh_c[256];
    __shared__ float sh_s[256];
    __shared__ unsigned int suf_c[256];
    __shared__ float suf_s[256];

    int tid = threadIdx.x;
    unsigned int lc[BPT];
    float lloss[BPT];            // per-bin total loss: c * softplus(center)
    unsigned int tc = 0;
    float tsum = 0.0f;
    #pragma unroll
    for (int j = 0; j < BPT; ++j) {
        int b = tid * BPT + j;
        unsigned int c = g_cnt[b];
        lc[j] = c;
        float lb = 0.0f;
        if (c > 0) {
            float center = ((float)b + 0.5f) * INV_BIN - XOFF;
            lb = (float)c * softplus_acc(center);
        }
        lloss[j] = lb;
        tc += c;
        tsum += lb;
    }
    sh_c[tid] = tc;
    sh_s[tid] = tsum;
    __syncthreads();

    if (tid == 0) {
        // exclusive suffix totals over the 256 thread-chunks
        unsigned int rc = 0; float rs = 0.0f;
        for (int i = 255; i >= 0; --i) {
            suf_c[i] = rc; suf_s[i] = rs;
            rc += sh_c[i]; rs += sh_s[i];
        }
    }
    __syncthreads();

    unsigned int n_pos = *g_npos;
    unsigned int n_neg = (unsigned int)n_total - n_pos;
    float pos_mean = (n_pos > 0) ? (*g_psum / (float)n_pos) : 0.0f;

    if (n_neg == 0) {
        if (tid == 0) out[0] = pos_mean;
        return;
    }

    // k = max(1024, rint(0.1 * n_neg)), clamped to n_neg (RNE matches jnp.round)
    float nf = (float)n_neg;
    int k = (int)rintf(nf * 0.1f);
    if (k < 1024) k = 1024;
    if ((unsigned int)k > n_neg) k = (int)n_neg;

    // walk own chunk from the top bin down; exactly one (tid, j) crosses k
    unsigned int run_c = suf_c[tid];
    float run_s = suf_s[tid];
    #pragma unroll
    for (int j = BPT - 1; j >= 0; --j) {
        unsigned int c = lc[j];
        float lb = lloss[j];
        if (c > 0 && run_c < (unsigned int)k && run_c + c >= (unsigned int)k) {
            unsigned int m = (unsigned int)k - run_c;
            float neg_sum = run_s + (float)m * (lb / (float)c);
            float neg_mean = neg_sum / (float)k;
            out[0] = pos_mean + neg_mean;
        }
        run_c += c;
        run_s += lb;
    }
}

extern "C" void kernel_launch(void* const* d_in, const int* in_sizes, int n_in,
                              void* d_out, int out_size, void* d_ws, size_t ws_size,
                              hipStream_t stream) {
    const float* logits  = (const float*)d_in[0];
    const float* targets = (const float*)d_in[1];
    float* out = (float*)d_out;
    int n_total = in_sizes[0];
    int n8 = n_total / 8;

    unsigned int* g_cnt  = (unsigned int*)d_ws;
    unsigned int* g_npos = (unsigned int*)((char*)d_ws + NBINS * 4);
    float*        g_psum = (float*)((char*)d_ws + NBINS * 4 + 4);

    hipMemsetAsync(d_ws, 0, NBINS * 4 + 8, stream);

    // 1024-thread blocks: 512 blocks = 2 blocks/CU * 16 waves = full residency;
    // 4x fewer global flush atomics than 2048x256.
    ohem_pass1<<<512, 1024, 0, stream>>>(logits, targets, g_cnt,
                                         g_npos, g_psum, n8, n_total);
    ohem_finalize<<<1, 256, 0, stream>>>(g_cnt, g_npos, g_psum, out, n_total);
}